// Round 11
// baseline (488.050 us; speedup 1.0000x reference)
//
#include <hip/hip_runtime.h>
#include <hip/hip_bf16.h>

typedef __bf16 bf16x8 __attribute__((ext_vector_type(8)));
typedef __bf16 bf16x4 __attribute__((ext_vector_type(4)));
typedef float  f32x4  __attribute__((ext_vector_type(4)));

constexpr int Ee = 8, Cc = 512, Mm = 1024, Hh = 4096, Tt = 2048;

// async global->LDS, 16B/lane. LDS dest wave-uniform base + lane*16 (m97/m104).
__device__ __forceinline__ void async16(void* lds, const void* g) {
  __builtin_amdgcn_global_load_lds(
      (const __attribute__((address_space(1))) void*)g,
      (__attribute__((address_space(3))) void*)lds, 16, 0, 0);
}

#define FENCE() asm volatile("" ::: "memory")
#define BARRIER() do { FENCE(); __builtin_amdgcn_s_barrier(); FENCE(); } while (0)

// Bijective XCD-chunked swizzle (m204).
__device__ __forceinline__ int xcd_swz(int id, int n) {
  const int q = n >> 3, r = n & 7;
  const int x = id & 7, k = id >> 3;
  return (x < r ? x * (q + 1) : r * (q + 1) + (x - r) * q) + k;
}

// ---------------------------------------------------------------------------
// 256x256 GEMM core, BK=64, 8 waves (2M x 4N), 2 barriers per K-tile.
// [ROUND-5 CORE — best measured: fc1=189us/727TF; r7 4-phase (208) and
//  r8/r10 1-barrier triple-buffer (196) both regressed. Do not re-derive.]
//   acc[mi][ni] = transposed fragments: D = mfma(bF, aF) -> rows=n, cols=t.
// Sync ledger (per tile t, dbuf = parity):
//   B0(entry): stage B(t+1)h0,h1 (slot last read in tile t-1, reads completed
//     before t-1's boundary barrier -> WAR-safe).
//   read aF[0..7] (16) + bF(ni01) (4).
//   B1: separates ALL waves' A(t)-reads from A(t+2) stage issues (same slot).
//   stage A(t+2)h0,h1; 32 MFMA (ni01); read bF(ni23) (4); 32 MFMA (ni23).
//   vmcnt(4): FIFO [A(t+1)4, B(t+1)4, A(t+2)4] -> drains tile t+1's needs,
//     keeps A(t+2) in flight across the boundary. Tail: vmcnt(0).
// Prologue: A0,B0 (8) + A1 (4); vmcnt(4) -> tile0 landed; barrier.
// LDS swizzle: 16B block, phys = logical ^ (row&7), via pre-swizzled global
//   source (involution both sides, rule #21). 0 bank conflicts (r4-r10).
// ---------------------------------------------------------------------------
__device__ __forceinline__ void gemm256(
    const __bf16* __restrict__ aT, const __bf16* __restrict__ bT, const int K,
    __bf16 (*Ab)[2][128][64], __bf16 (*Bb)[2][128][64],
    f32x4 (&acc)[8][4]) {
  const int tid = threadIdx.x;
  const int lane = tid & 63, wid = tid >> 6;
  const int wr = wid >> 2, wcn = wid & 3;
  const int l8 = lane >> 3;
  const int colSwzE = (((lane & 7) ^ l8) << 3);  // pre-swizzled source col
  const int NT = K >> 6;

  int pblk[2];
  pblk[0] = (lane >> 4) ^ (lane & 7);
  pblk[1] = (4 + (lane >> 4)) ^ (lane & 7);

  bf16x8 aF[8][2];
  bf16x8 bF[2][2];

  auto STAGE = [&](int s, int u) {
    if (s >= NT) return;
    const int d = s & 1;
    if (u < 2) {
      const __bf16* src = aT + (size_t)(u * 128 + wid * 16 + l8) * K + s * 64 + colSwzE;
#pragma unroll
      for (int i = 0; i < 2; ++i)
        async16(&Ab[d][u][wid * 16 + i * 8][0], src + (size_t)(i * 8) * K);
    } else {
      const __bf16* src = bT + (size_t)((u - 2) * 128 + wid * 16 + l8) * K + s * 64 + colSwzE;
#pragma unroll
      for (int i = 0; i < 2; ++i)
        async16(&Bb[d][u - 2][wid * 16 + i * 8][0], src + (size_t)(i * 8) * K);
    }
  };

  // prologue
  STAGE(0, 0); STAGE(0, 1); STAGE(0, 2); STAGE(0, 3);
  STAGE(1, 0); STAGE(1, 1);
  asm volatile("s_waitcnt vmcnt(4)" ::: "memory");
  BARRIER();

  for (int t = 0; t < NT; ++t) {
    const int d = t & 1;
    const char* pa = (const char*)&Ab[d][wr][0][0];
    const char* pb = (const char*)&Bb[d][wcn >> 1][0][0];
    const int brow = (wcn & 1) * 64;

    // stage next tile's B (slot freed at entry barrier)
    STAGE(t + 1, 2); STAGE(t + 1, 3);

    // read all A frags + B ni0-1
#pragma unroll
    for (int mi = 0; mi < 8; ++mi)
#pragma unroll
      for (int kh = 0; kh < 2; ++kh)
        aF[mi][kh] = *(const bf16x8*)(pa + (mi * 16 + (lane & 15)) * 128 + pblk[kh] * 16);
#pragma unroll
    for (int ni = 0; ni < 2; ++ni)
#pragma unroll
      for (int kh = 0; kh < 2; ++kh)
        bF[ni][kh] = *(const bf16x8*)(pb + (brow + ni * 16 + (lane & 15)) * 128 + pblk[kh] * 16);

    BARRIER();  // B1: A-slot WAR fence (all waves' A reads issued & drained)

    // stage A(t+2) into the just-freed A slot; floats across tile boundary
    STAGE(t + 2, 0); STAGE(t + 2, 1);

    __builtin_amdgcn_s_setprio(1);
#pragma unroll
    for (int mi = 0; mi < 8; ++mi)
#pragma unroll
      for (int ni = 0; ni < 2; ++ni)
#pragma unroll
        for (int kh = 0; kh < 2; ++kh)
          acc[mi][ni] = __builtin_amdgcn_mfma_f32_16x16x32_bf16(bF[ni][kh], aF[mi][kh], acc[mi][ni], 0, 0, 0);
    __builtin_amdgcn_s_setprio(0);

    // read B ni2-3, second MFMA cluster
#pragma unroll
    for (int ni = 0; ni < 2; ++ni)
#pragma unroll
      for (int kh = 0; kh < 2; ++kh)
        bF[ni][kh] = *(const bf16x8*)(pb + (brow + (2 + ni) * 16 + (lane & 15)) * 128 + pblk[kh] * 16);

    __builtin_amdgcn_s_setprio(1);
#pragma unroll
    for (int mi = 0; mi < 8; ++mi)
#pragma unroll
      for (int ni = 0; ni < 2; ++ni)
#pragma unroll
        for (int kh = 0; kh < 2; ++kh)
          acc[mi][2 + ni] = __builtin_amdgcn_mfma_f32_16x16x32_bf16(bF[ni][kh], aF[mi][kh], acc[mi][2 + ni], 0, 0, 0);
    __builtin_amdgcn_s_setprio(0);

    if (t < NT - 2) { asm volatile("s_waitcnt vmcnt(4)" ::: "memory"); }
    else            { asm volatile("s_waitcnt vmcnt(0)" ::: "memory"); }
    BARRIER();  // tile boundary
  }
}

// ---------------------------------------------------------------------------
// fc1: h = relu(xb @ w1b^T + b1) -> bf16 hb.  acc is C^T: row=n, col=t.
// t-fastest decode: 32 co-resident blocks/XCD = 4 n x 8 t -> xb panel (4 MiB)
// fits the XCD L2 and is reused across n-rounds; w1b streamed once.
// ---------------------------------------------------------------------------
__global__ __launch_bounds__(512, 2) void fc1g_kernel(
    const __bf16* __restrict__ xb, int eOffA,
    const __bf16* __restrict__ w1b, int eOffB,
    const float* __restrict__ b1, __bf16* __restrict__ hb,
    int e0, int t_base, int tcap, int nbT) {
  __shared__ __bf16 Ab[2][2][128][64];
  __shared__ __bf16 Bb[2][2][128][64];
  const int nbN = Hh / 256;  // 16
  const int id = xcd_swz(blockIdx.x, gridDim.x);
  const int z = id / (nbN * nbT);
  const int rm = id % (nbN * nbT);
  const int tblk = (rm % nbT) * 256, nblk = (rm / nbT) * 256;
  const int lane = threadIdx.x & 63, wid = threadIdx.x >> 6;
  const int wr = wid >> 2, wcn = wid & 3;

  const __bf16* aT = xb + ((size_t)(eOffA + z) * Tt + t_base + tblk) * Mm;
  const __bf16* bT = w1b + ((size_t)(eOffB + z) * Hh + nblk) * Mm;

  f32x4 acc[8][4];
#pragma unroll
  for (int i = 0; i < 8; ++i)
#pragma unroll
    for (int j = 0; j < 4; ++j) acc[i][j] = (f32x4){0.f, 0.f, 0.f, 0.f};

  gemm256(aT, bT, Mm, Ab, Bb, acc);

  const float* bias = b1 + (size_t)(e0 + z) * Hh;
#pragma unroll
  for (int ni = 0; ni < 4; ++ni) {
    const int n0 = nblk + wcn * 64 + ni * 16 + ((lane >> 4) << 2);
    const f32x4 b4 = *(const f32x4*)(bias + n0);
#pragma unroll
    for (int mi = 0; mi < 8; ++mi) {
      const int trow = tblk + wr * 128 + mi * 16 + (lane & 15);
      f32x4 v = acc[mi][ni];
      bf16x4 o;
#pragma unroll
      for (int rr = 0; rr < 4; ++rr) {
        float f = v[rr] + b4[rr];
        o[rr] = (__bf16)(f > 0.f ? f : 0.f);
      }
      *(bf16x4*)(hb + ((size_t)z * tcap + trow) * Hh + n0) = o;
    }
  }
}

// ---------------------------------------------------------------------------
// fc2: out = hb @ w2t^T + b2 -> fp32 scattered to [B,E,C,M]. acc: row=m, col=t.
// ---------------------------------------------------------------------------
__global__ __launch_bounds__(512, 2) void fc2g_kernel(
    const __bf16* __restrict__ hb, int tcap,
    const __bf16* __restrict__ w2t, int eOffB,
    const float* __restrict__ b2, float* __restrict__ out,
    int e0, int t_base, int nbT) {
  __shared__ __bf16 Ab[2][2][128][64];
  __shared__ __bf16 Bb[2][2][128][64];
  const int nbN = Mm / 256;  // 4
  const int id = xcd_swz(blockIdx.x, gridDim.x);
  const int z = id / (nbN * nbT);
  const int rm = id % (nbN * nbT);
  const int tblk = (rm % nbT) * 256, nblk = (rm / nbT) * 256;
  const int lane = threadIdx.x & 63, wid = threadIdx.x >> 6;
  const int wr = wid >> 2, wcn = wid & 3;
  const int e = e0 + z;

  const __bf16* aT = hb + ((size_t)z * tcap + tblk) * Hh;
  const __bf16* bT = w2t + ((size_t)(eOffB + z) * Mm + nblk) * Hh;

  f32x4 acc[8][4];
#pragma unroll
  for (int i = 0; i < 8; ++i)
#pragma unroll
    for (int j = 0; j < 4; ++j) acc[i][j] = (f32x4){0.f, 0.f, 0.f, 0.f};

  gemm256(aT, bT, Hh, Ab, Bb, acc);

  const float* bias = b2 + (size_t)e * Mm;
#pragma unroll
  for (int ni = 0; ni < 4; ++ni) {
    const int m0 = nblk + wcn * 64 + ni * 16 + ((lane >> 4) << 2);
    const f32x4 b4 = *(const f32x4*)(bias + m0);
#pragma unroll
    for (int mi = 0; mi < 8; ++mi) {
      const int t = t_base + tblk + wr * 128 + mi * 16 + (lane & 15);
      const int bb = t >> 9, cc = t & 511;
      f32x4 v = acc[mi][ni];
#pragma unroll
      for (int rr = 0; rr < 4; ++rr) v[rr] += b4[rr];
      *(f32x4*)(out + ((((size_t)bb * Ee + e) * Cc + cc) << 10) + m0) = v;
    }
  }
}

// ---------------------------------------------------------------------------
// Merged prepass (Path A): one launch does all three conversions.
//   blocks [0,8192):       x [B,E,C,M] fp32 -> xb [z][T][M] bf16 (permute)
//   blocks [8192,24576):   w1 fp32 -> w1b bf16 (linear)
//   blocks [24576,32768):  w2 [E][H][M] fp32 -> w2t [z][M][H] bf16 (transpose)
// Removes 2 inter-kernel full-device drains; phases tile the CU array together.
// ---------------------------------------------------------------------------
__global__ __launch_bounds__(256) void prep_all_kernel(
    const float* __restrict__ x, const float* __restrict__ w1,
    const float* __restrict__ w2, __bf16* __restrict__ xb,
    __bf16* __restrict__ w1b, __bf16* __restrict__ w2t) {
  __shared__ __bf16 tile[64][68];
  const int bid = blockIdx.x;
  if (bid < 8192) {
    size_t idx8 = (size_t)bid * 256 + threadIdx.x;
    int m8 = (int)(idx8 & 127);
    int t = (int)((idx8 >> 7) & 2047);
    int z = (int)(idx8 >> 18);
    int b = t >> 9, c = t & 511;
    const float* src = x + ((((size_t)b * Ee + z) * Cc + c) << 10) + (m8 << 3);
    f32x4 v0 = *(const f32x4*)src;
    f32x4 v1 = *(const f32x4*)(src + 4);
    bf16x8 o;
    o[0] = (__bf16)v0[0]; o[1] = (__bf16)v0[1]; o[2] = (__bf16)v0[2]; o[3] = (__bf16)v0[3];
    o[4] = (__bf16)v1[0]; o[5] = (__bf16)v1[1]; o[6] = (__bf16)v1[2]; o[7] = (__bf16)v1[3];
    *(bf16x8*)(xb + (idx8 << 3)) = o;
  } else if (bid < 24576) {
    size_t i8 = (size_t)(bid - 8192) * 256 + threadIdx.x;
    const float* src = w1 + (i8 << 3);
    f32x4 v0 = *(const f32x4*)src;
    f32x4 v1 = *(const f32x4*)(src + 4);
    bf16x8 o;
    o[0] = (__bf16)v0[0]; o[1] = (__bf16)v0[1]; o[2] = (__bf16)v0[2]; o[3] = (__bf16)v0[3];
    o[4] = (__bf16)v1[0]; o[5] = (__bf16)v1[1]; o[6] = (__bf16)v1[2]; o[7] = (__bf16)v1[3];
    *(bf16x8*)(w1b + (i8 << 3)) = o;
  } else {
    const int tb = bid - 24576;            // 1024 tiles/expert * 8
    const int z = tb >> 10;
    const int rem = tb & 1023;
    const int m0 = (rem & 15) * 64;        // 16 m-tiles
    const int h0 = (rem >> 4) * 64;        // 64 h-tiles
    const int tid = threadIdx.x;
    const int cg = tid & 15, rg = tid >> 4;
#pragma unroll
    for (int p = 0; p < 4; ++p) {
      int hl = rg + p * 16;
      f32x4 v = *(const f32x4*)(w2 + (((size_t)z * Hh + h0 + hl) << 10) + m0 + (cg << 2));
#pragma unroll
      for (int i = 0; i < 4; ++i) tile[(cg << 2) + i][hl] = (__bf16)v[i];
    }
    __syncthreads();
#pragma unroll
    for (int p = 0; p < 4; ++p) {
      int ml = rg + p * 16;
      uint2 pk = *(const uint2*)(&tile[ml][cg << 2]);
      *(uint2*)(w2t + ((size_t)z * Mm + m0 + ml) * Hh + h0 + (cg << 2)) = pk;
    }
  }
}

// ---------------------------------------------------------------------------
// Standalone prepasses (fallback paths B/C/D).
// ---------------------------------------------------------------------------
__global__ __launch_bounds__(256) void cvt_x_kernel(
    const float* __restrict__ x, __bf16* __restrict__ xb, int e0) {
  size_t idx8 = (size_t)blockIdx.x * 256 + threadIdx.x;
  int m8 = (int)(idx8 & 127);
  int t = (int)((idx8 >> 7) & 2047);
  int z = (int)(idx8 >> 18);
  int b = t >> 9, c = t & 511, e = e0 + z;
  const float* src = x + ((((size_t)b * Ee + e) * Cc + c) << 10) + (m8 << 3);
  f32x4 v0 = *(const f32x4*)src;
  f32x4 v1 = *(const f32x4*)(src + 4);
  bf16x8 o;
  o[0] = (__bf16)v0[0]; o[1] = (__bf16)v0[1]; o[2] = (__bf16)v0[2]; o[3] = (__bf16)v0[3];
  o[4] = (__bf16)v1[0]; o[5] = (__bf16)v1[1]; o[6] = (__bf16)v1[2]; o[7] = (__bf16)v1[3];
  *(bf16x8*)(xb + (idx8 << 3)) = o;
}

__global__ __launch_bounds__(256) void cvt_lin_kernel(
    const float* __restrict__ in, __bf16* __restrict__ outb) {
  size_t i8 = (size_t)blockIdx.x * 256 + threadIdx.x;
  const float* src = in + (i8 << 3);
  f32x4 v0 = *(const f32x4*)src;
  f32x4 v1 = *(const f32x4*)(src + 4);
  bf16x8 o;
  o[0] = (__bf16)v0[0]; o[1] = (__bf16)v0[1]; o[2] = (__bf16)v0[2]; o[3] = (__bf16)v0[3];
  o[4] = (__bf16)v1[0]; o[5] = (__bf16)v1[1]; o[6] = (__bf16)v1[2]; o[7] = (__bf16)v1[3];
  *(bf16x8*)(outb + (i8 << 3)) = o;
}

__global__ __launch_bounds__(256) void tr_w2_kernel(
    const float* __restrict__ w2, __bf16* __restrict__ w2t, int e0) {
  __shared__ __bf16 tile[64][68];
  const int z = blockIdx.z, e = e0 + z;
  const int m0 = blockIdx.x * 64, h0 = blockIdx.y * 64;
  const int tid = threadIdx.x;
  const int cg = tid & 15, rg = tid >> 4;
#pragma unroll
  for (int p = 0; p < 4; ++p) {
    int hl = rg + p * 16;
    f32x4 v = *(const f32x4*)(w2 + (((size_t)e * Hh + h0 + hl) << 10) + m0 + (cg << 2));
#pragma unroll
    for (int i = 0; i < 4; ++i) tile[(cg << 2) + i][hl] = (__bf16)v[i];
  }
  __syncthreads();
#pragma unroll
  for (int p = 0; p < 4; ++p) {
    int ml = rg + p * 16;
    uint2 pk = *(const uint2*)(&tile[ml][cg << 2]);
    *(uint2*)(w2t + ((size_t)z * Mm + m0 + ml) * Hh + h0 + (cg << 2)) = pk;
  }
}

// ---------------------------------------------------------------------------
extern "C" void kernel_launch(void* const* d_in, const int* in_sizes, int n_in,
                              void* d_out, int out_size, void* d_ws, size_t ws_size,
                              hipStream_t stream) {
  const float* x  = (const float*)d_in[0];
  const float* w1 = (const float*)d_in[1];
  const float* b1 = (const float*)d_in[2];
  const float* w2 = (const float*)d_in[3];
  const float* b2 = (const float*)d_in[4];
  float* out = (float*)d_out;

  const size_t xbS = (size_t)Tt * Mm * 2;  //  4 MiB / expert
  const size_t w1S = (size_t)Hh * Mm * 2;  //  8 MiB / expert
  const size_t w2S = (size_t)Mm * Hh * 2;  //  8 MiB / expert
  const size_t hbS = (size_t)Tt * Hh * 2;  // 16 MiB / expert
  char* ws = (char*)d_ws;

  if (ws_size >= Ee * (xbS + w1S + w2S + hbS)) {
    // Path A: everything resident (288 MiB). Merged prepass + full-width GEMMs.
    __bf16* xb  = (__bf16*)ws;
    __bf16* w1b = (__bf16*)(ws + Ee * xbS);
    __bf16* w2t = (__bf16*)(ws + Ee * (xbS + w1S));
    __bf16* hb  = (__bf16*)(ws + Ee * (xbS + w1S + w2S));
    prep_all_kernel<<<32768, 256, 0, stream>>>(x, w1, w2, xb, w1b, w2t);
    fc1g_kernel<<<(Hh / 256) * (Tt / 256) * Ee, 512, 0, stream>>>(xb, 0, w1b, 0, b1, hb, 0, 0, Tt, Tt / 256);
    fc2g_kernel<<<(Mm / 256) * (Tt / 256) * Ee, 512, 0, stream>>>(hb, Tt, w2t, 0, b2, out, 0, 0, Tt / 256);
  } else if (ws_size >= Ee * (xbS + w1S + w2S) + hbS) {
    // Path B: all conversions resident; hb grouped.
    __bf16* xb  = (__bf16*)ws;
    __bf16* w1b = (__bf16*)(ws + Ee * xbS);
    __bf16* w2t = (__bf16*)(ws + Ee * (xbS + w1S));
    __bf16* hb  = (__bf16*)(ws + Ee * (xbS + w1S + w2S));
    int Gh = (int)((ws_size - Ee * (xbS + w1S + w2S)) / hbS);
    if (Gh > Ee) Gh = Ee;
    prep_all_kernel<<<32768, 256, 0, stream>>>(x, w1, w2, xb, w1b, w2t);
    for (int e0 = 0; e0 < Ee; e0 += Gh) {
      int g = (Ee - e0) < Gh ? (Ee - e0) : Gh;
      fc1g_kernel<<<(Hh / 256) * (Tt / 256) * g, 512, 0, stream>>>(xb, e0, w1b, e0, b1, hb, e0, 0, Tt, Tt / 256);
      fc2g_kernel<<<(Mm / 256) * (Tt / 256) * g, 512, 0, stream>>>(hb, Tt, w2t, e0, b2, out, e0, 0, Tt / 256);
    }
  } else if (ws_size >= xbS + w1S + w2S + hbS) {
    // Path C: full pipeline grouped by G experts.
    int G = (int)(ws_size / (xbS + w1S + w2S + hbS));
    if (G > Ee) G = Ee;
    __bf16* xb  = (__bf16*)ws;
    __bf16* w1b = (__bf16*)(ws + (size_t)G * xbS);
    __bf16* w2t = (__bf16*)(ws + (size_t)G * (xbS + w1S));
    __bf16* hb  = (__bf16*)(ws + (size_t)G * (xbS + w1S + w2S));
    for (int e0 = 0; e0 < Ee; e0 += G) {
      int g = (Ee - e0) < G ? (Ee - e0) : G;
      cvt_x_kernel<<<g * 1024, 256, 0, stream>>>(x, xb, e0);
      cvt_lin_kernel<<<g * 2048, 256, 0, stream>>>(w1 + (size_t)e0 * Hh * Mm, w1b);
      tr_w2_kernel<<<dim3(Mm / 64, Hh / 64, g), 256, 0, stream>>>(w2, w2t, e0);
      fc1g_kernel<<<(Hh / 256) * (Tt / 256) * g, 512, 0, stream>>>(xb, 0, w1b, 0, b1, hb, e0, 0, Tt, Tt / 256);
      fc2g_kernel<<<(Mm / 256) * (Tt / 256) * g, 512, 0, stream>>>(hb, Tt, w2t, 0, b2, out, e0, 0, Tt / 256);
    }
  } else {
    // Path D: one expert, T chunked (256-row granularity).
    __bf16* xb  = (__bf16*)ws;
    __bf16* w1b = (__bf16*)(ws + xbS);
    __bf16* w2t = (__bf16*)(ws + xbS + w1S);
    __bf16* hb  = (__bf16*)(ws + xbS + w1S + w2S);
    size_t rem = ws_size > (xbS + w1S + w2S) ? ws_size - (xbS + w1S + w2S) : 0;
    int Tc = (int)(rem / ((size_t)Hh * 2)) & ~255;
    if (Tc > Tt) Tc = Tt;
    if (Tc < 256) Tc = 256;
    for (int e0 = 0; e0 < Ee; ++e0) {
      cvt_x_kernel<<<1024, 256, 0, stream>>>(x, xb, e0);
      cvt_lin_kernel<<<2048, 256, 0, stream>>>(w1 + (size_t)e0 * Hh * Mm, w1b);
      tr_w2_kernel<<<dim3(Mm / 64, Hh / 64, 1), 256, 0, stream>>>(w2, w2t, e0);
      for (int t0 = 0; t0 < Tt; t0 += Tc) {
        int tc = (Tt - t0) < Tc ? (Tt - t0) : Tc;
        fc1g_kernel<<<(Hh / 256) * (tc / 256), 512, 0, stream>>>(xb, 0, w1b, 0, b1, hb, e0, t0, Tc, tc / 256);
        fc2g_kernel<<<(Mm / 256) * (tc / 256), 512, 0, stream>>>(hb, Tc, w2t, 0, b2, out, e0, t0, tc / 256);
      }
    }
  }
}

// Round 14
// 459.964 us; speedup vs baseline: 1.0611x; 1.0611x over previous
//
#include <hip/hip_runtime.h>
#include <hip/hip_bf16.h>

typedef __bf16 bf16x8 __attribute__((ext_vector_type(8)));
typedef __bf16 bf16x4 __attribute__((ext_vector_type(4)));
typedef float  f32x4  __attribute__((ext_vector_type(4)));

constexpr int Ee = 8, Cc = 512, Mm = 1024, Hh = 4096, Tt = 2048;

// async global->LDS, 16B/lane. LDS dest wave-uniform base + lane*16 (m97/m104).
__device__ __forceinline__ void async16(void* lds, const void* g) {
  __builtin_amdgcn_global_load_lds(
      (const __attribute__((address_space(1))) void*)g,
      (__attribute__((address_space(3))) void*)lds, 16, 0, 0);
}

#define FENCE() asm volatile("" ::: "memory")
#define BARRIER() do { FENCE(); __builtin_amdgcn_s_barrier(); FENCE(); } while (0)

// Bijective XCD-chunked swizzle (m204).
__device__ __forceinline__ int xcd_swz(int id, int n) {
  const int q = n >> 3, r = n & 7;
  const int x = id & 7, k = id >> 3;
  return (x < r ? x * (q + 1) : r * (q + 1) + (x - r) * q) + k;
}

// ---------------------------------------------------------------------------
// 256x256 GEMM, BK=64, 8 waves (2M x 4N), 2 barriers/K-tile. [r5 CORE —
// best measured 189us/727TF fc1; r7 4-phase (208), r8/r10 1-barrier-3buf
// (196), r11 t-fastest decode (255) all regressed. Do not re-derive.]
// Split into PRO (issue prologue loads) + BODY (wait + K-loop) so a chained
// caller can hide the next tile's prologue under the previous epilogue.
// Ledger: see r5. LDS swizzle: phys16B-blk = logical ^ (row&7), via
// pre-swizzled global source (rule #21). 0 bank conflicts (r4-r11).
// ---------------------------------------------------------------------------
#define GEOM_LOCALS \
  const int tid = threadIdx.x; \
  const int lane = tid & 63, wid = tid >> 6; \
  const int l8 = lane >> 3; \
  const int colSwzE = (((lane & 7) ^ l8) << 3); \
  const int NT = K >> 6;

#define STAGE_IMPL \
  auto STAGE = [&](int s, int u) { \
    if (s >= NT) return; \
    const int d = s & 1; \
    if (u < 2) { \
      const __bf16* src = aT + (size_t)(u * 128 + wid * 16 + l8) * K + s * 64 + colSwzE; \
      _Pragma("unroll") \
      for (int i = 0; i < 2; ++i) \
        async16(&Ab[d][u][wid * 16 + i * 8][0], src + (size_t)(i * 8) * K); \
    } else { \
      const __bf16* src = bT + (size_t)((u - 2) * 128 + wid * 16 + l8) * K + s * 64 + colSwzE; \
      _Pragma("unroll") \
      for (int i = 0; i < 2; ++i) \
        async16(&Bb[d][u - 2][wid * 16 + i * 8][0], src + (size_t)(i * 8) * K); \
    } \
  };

__device__ __forceinline__ void gemm_pro(
    const __bf16* __restrict__ aT, const __bf16* __restrict__ bT, const int K,
    __bf16 (*Ab)[2][128][64], __bf16 (*Bb)[2][128][64]) {
  GEOM_LOCALS
  STAGE_IMPL
  STAGE(0, 0); STAGE(0, 1); STAGE(0, 2); STAGE(0, 3);
  STAGE(1, 0); STAGE(1, 1);
}

__device__ __forceinline__ void gemm_body(
    const __bf16* __restrict__ aT, const __bf16* __restrict__ bT, const int K,
    __bf16 (*Ab)[2][128][64], __bf16 (*Bb)[2][128][64],
    f32x4 (&acc)[8][4]) {
  GEOM_LOCALS
  STAGE_IMPL
  const int wr = wid >> 2, wcn = wid & 3;
  int pblk[2];
  pblk[0] = (lane >> 4) ^ (lane & 7);
  pblk[1] = (4 + (lane >> 4)) ^ (lane & 7);

  bf16x8 aF[8][2];
  bf16x8 bF[2][2];

  asm volatile("s_waitcnt vmcnt(4)" ::: "memory");
  BARRIER();

  for (int t = 0; t < NT; ++t) {
    const int d = t & 1;
    const char* pa = (const char*)&Ab[d][wr][0][0];
    const char* pb = (const char*)&Bb[d][wcn >> 1][0][0];
    const int brow = (wcn & 1) * 64;

    STAGE(t + 1, 2); STAGE(t + 1, 3);

#pragma unroll
    for (int mi = 0; mi < 8; ++mi)
#pragma unroll
      for (int kh = 0; kh < 2; ++kh)
        aF[mi][kh] = *(const bf16x8*)(pa + (mi * 16 + (lane & 15)) * 128 + pblk[kh] * 16);
#pragma unroll
    for (int ni = 0; ni < 2; ++ni)
#pragma unroll
      for (int kh = 0; kh < 2; ++kh)
        bF[ni][kh] = *(const bf16x8*)(pb + (brow + ni * 16 + (lane & 15)) * 128 + pblk[kh] * 16);

    BARRIER();  // A-slot WAR fence

    STAGE(t + 2, 0); STAGE(t + 2, 1);

    __builtin_amdgcn_s_setprio(1);
#pragma unroll
    for (int mi = 0; mi < 8; ++mi)
#pragma unroll
      for (int ni = 0; ni < 2; ++ni)
#pragma unroll
        for (int kh = 0; kh < 2; ++kh)
          acc[mi][ni] = __builtin_amdgcn_mfma_f32_16x16x32_bf16(bF[ni][kh], aF[mi][kh], acc[mi][ni], 0, 0, 0);
    __builtin_amdgcn_s_setprio(0);

#pragma unroll
    for (int ni = 0; ni < 2; ++ni)
#pragma unroll
      for (int kh = 0; kh < 2; ++kh)
        bF[ni][kh] = *(const bf16x8*)(pb + (brow + (2 + ni) * 16 + (lane & 15)) * 128 + pblk[kh] * 16);

    __builtin_amdgcn_s_setprio(1);
#pragma unroll
    for (int mi = 0; mi < 8; ++mi)
#pragma unroll
      for (int ni = 0; ni < 2; ++ni)
#pragma unroll
        for (int kh = 0; kh < 2; ++kh)
          acc[mi][2 + ni] = __builtin_amdgcn_mfma_f32_16x16x32_bf16(bF[ni][kh], aF[mi][kh], acc[mi][2 + ni], 0, 0, 0);
    __builtin_amdgcn_s_setprio(0);

    if (t < NT - 2) { asm volatile("s_waitcnt vmcnt(4)" ::: "memory"); }
    else            { asm volatile("s_waitcnt vmcnt(0)" ::: "memory"); }
    BARRIER();
  }
}

// ---------------------------------------------------------------------------
// fc1 persistent: 32 blocks/expert, each chains 4 n-tiles (full 256x1024 row
// band). Next tile's prologue issues BEFORE the epilogue stores -> HBM fill
// latency hides under the stores. acc is C^T: row=n, col=t.
// ---------------------------------------------------------------------------
__global__ __launch_bounds__(512, 2) void fc1p_kernel(
    const __bf16* __restrict__ xb, int eOffA,
    const __bf16* __restrict__ w1b, int eOffB,
    const float* __restrict__ b1, __bf16* __restrict__ hb,
    int e0, int tcap) {
  __shared__ __bf16 Ab[2][2][128][64];
  __shared__ __bf16 Bb[2][2][128][64];
  const int id = xcd_swz(blockIdx.x, gridDim.x);
  const int z = id >> 5;
  const int rm = id & 31;
  const int ngrp = rm & 3;             // 4 n-groups of 4 tiles
  const int tblk = (rm >> 2) * 256;    // 8 t-blocks
  const int lane = threadIdx.x & 63, wid = threadIdx.x >> 6;
  const int wr = wid >> 2, wcn = wid & 3;

  const __bf16* aT = xb + ((size_t)(eOffA + z) * Tt + tblk) * Mm;
  const float* bias = b1 + (size_t)(e0 + z) * Hh;

  const __bf16* bT = w1b + ((size_t)(eOffB + z) * Hh + (ngrp * 4 + 0) * 256) * Mm;
  gemm_pro(aT, bT, Mm, Ab, Bb);

#pragma unroll 1
  for (int i = 0; i < 4; ++i) {
    const int nblk = (ngrp * 4 + i) * 256;
    f32x4 acc[8][4];
#pragma unroll
    for (int a = 0; a < 8; ++a)
#pragma unroll
      for (int b = 0; b < 4; ++b) acc[a][b] = (f32x4){0.f, 0.f, 0.f, 0.f};

    gemm_body(aT, bT, Mm, Ab, Bb, acc);

    // chain: issue next tile's prologue before the epilogue stores
    if (i < 3) {
      bT = w1b + ((size_t)(eOffB + z) * Hh + (ngrp * 4 + i + 1) * 256) * Mm;
      gemm_pro(aT, bT, Mm, Ab, Bb);
    }

#pragma unroll
    for (int ni = 0; ni < 4; ++ni) {
      const int n0 = nblk + wcn * 64 + ni * 16 + ((lane >> 4) << 2);
      const f32x4 b4 = *(const f32x4*)(bias + n0);
#pragma unroll
      for (int mi = 0; mi < 8; ++mi) {
        const int trow = tblk + wr * 128 + mi * 16 + (lane & 15);
        f32x4 v = acc[mi][ni];
        bf16x4 o;
#pragma unroll
        for (int rr = 0; rr < 4; ++rr) {
          float f = v[rr] + b4[rr];
          o[rr] = (__bf16)(f > 0.f ? f : 0.f);
        }
        *(bf16x4*)(hb + ((size_t)z * tcap + trow) * Hh + n0) = o;
      }
    }
  }
}

// ---------------------------------------------------------------------------
// fc1 fallback (Path D, T-chunked). n-fastest decode (r10-proven).
// ---------------------------------------------------------------------------
__global__ __launch_bounds__(512, 2) void fc1g_kernel(
    const __bf16* __restrict__ xb, int eOffA,
    const __bf16* __restrict__ w1b, int eOffB,
    const float* __restrict__ b1, __bf16* __restrict__ hb,
    int e0, int t_base, int tcap, int nbT) {
  __shared__ __bf16 Ab[2][2][128][64];
  __shared__ __bf16 Bb[2][2][128][64];
  const int nbN = Hh / 256;
  const int id = xcd_swz(blockIdx.x, gridDim.x);
  const int z = id / (nbN * nbT);
  const int rm = id % (nbN * nbT);
  const int tblk = (rm / nbN) * 256, nblk = (rm % nbN) * 256;
  const int lane = threadIdx.x & 63, wid = threadIdx.x >> 6;
  const int wr = wid >> 2, wcn = wid & 3;

  const __bf16* aT = xb + ((size_t)(eOffA + z) * Tt + t_base + tblk) * Mm;
  const __bf16* bT = w1b + ((size_t)(eOffB + z) * Hh + nblk) * Mm;

  f32x4 acc[8][4];
#pragma unroll
  for (int i = 0; i < 8; ++i)
#pragma unroll
    for (int j = 0; j < 4; ++j) acc[i][j] = (f32x4){0.f, 0.f, 0.f, 0.f};

  gemm_pro(aT, bT, Mm, Ab, Bb);
  gemm_body(aT, bT, Mm, Ab, Bb, acc);

  const float* bias = b1 + (size_t)(e0 + z) * Hh;
#pragma unroll
  for (int ni = 0; ni < 4; ++ni) {
    const int n0 = nblk + wcn * 64 + ni * 16 + ((lane >> 4) << 2);
    const f32x4 b4 = *(const f32x4*)(bias + n0);
#pragma unroll
    for (int mi = 0; mi < 8; ++mi) {
      const int trow = tblk + wr * 128 + mi * 16 + (lane & 15);
      f32x4 v = acc[mi][ni];
      bf16x4 o;
#pragma unroll
      for (int rr = 0; rr < 4; ++rr) {
        float f = v[rr] + b4[rr];
        o[rr] = (__bf16)(f > 0.f ? f : 0.f);
      }
      *(bf16x4*)(hb + ((size_t)z * tcap + trow) * Hh + n0) = o;
    }
  }
}

// ---------------------------------------------------------------------------
// fc2: out = hb @ w2t^T + b2 -> fp32 scattered. n-fastest decode (r10).
// ---------------------------------------------------------------------------
__global__ __launch_bounds__(512, 2) void fc2g_kernel(
    const __bf16* __restrict__ hb, int tcap,
    const __bf16* __restrict__ w2t, int eOffB,
    const float* __restrict__ b2, float* __restrict__ out,
    int e0, int t_base, int nbT) {
  __shared__ __bf16 Ab[2][2][128][64];
  __shared__ __bf16 Bb[2][2][128][64];
  const int nbN = Mm / 256;
  const int id = xcd_swz(blockIdx.x, gridDim.x);
  const int z = id / (nbN * nbT);
  const int rm = id % (nbN * nbT);
  const int tblk = (rm / nbN) * 256, nblk = (rm % nbN) * 256;
  const int lane = threadIdx.x & 63, wid = threadIdx.x >> 6;
  const int wr = wid >> 2, wcn = wid & 3;
  const int e = e0 + z;

  const __bf16* aT = hb + ((size_t)z * tcap + tblk) * Hh;
  const __bf16* bT = w2t + ((size_t)(eOffB + z) * Mm + nblk) * Hh;

  f32x4 acc[8][4];
#pragma unroll
  for (int i = 0; i < 8; ++i)
#pragma unroll
    for (int j = 0; j < 4; ++j) acc[i][j] = (f32x4){0.f, 0.f, 0.f, 0.f};

  gemm_pro(aT, bT, Hh, Ab, Bb);
  gemm_body(aT, bT, Hh, Ab, Bb, acc);

  const float* bias = b2 + (size_t)e * Mm;
#pragma unroll
  for (int ni = 0; ni < 4; ++ni) {
    const int m0 = nblk + wcn * 64 + ni * 16 + ((lane >> 4) << 2);
    const f32x4 b4 = *(const f32x4*)(bias + m0);
#pragma unroll
    for (int mi = 0; mi < 8; ++mi) {
      const int t = t_base + tblk + wr * 128 + mi * 16 + (lane & 15);
      const int bb = t >> 9, cc = t & 511;
      f32x4 v = acc[mi][ni];
#pragma unroll
      for (int rr = 0; rr < 4; ++rr) v[rr] += b4[rr];
      *(f32x4*)(out + ((((size_t)bb * Ee + e) * Cc + cc) << 10) + m0) = v;
    }
  }
}

// ---------------------------------------------------------------------------
// Merged prepass (Paths A/B): one launch, all three conversions.
// ---------------------------------------------------------------------------
__global__ __launch_bounds__(256) void prep_all_kernel(
    const float* __restrict__ x, const float* __restrict__ w1,
    const float* __restrict__ w2, __bf16* __restrict__ xb,
    __bf16* __restrict__ w1b, __bf16* __restrict__ w2t) {
  __shared__ __bf16 tile[64][68];
  const int bid = blockIdx.x;
  if (bid < 8192) {
    size_t idx8 = (size_t)bid * 256 + threadIdx.x;
    int m8 = (int)(idx8 & 127);
    int t = (int)((idx8 >> 7) & 2047);
    int z = (int)(idx8 >> 18);
    int b = t >> 9, c = t & 511;
    const float* src = x + ((((size_t)b * Ee + z) * Cc + c) << 10) + (m8 << 3);
    f32x4 v0 = *(const f32x4*)src;
    f32x4 v1 = *(const f32x4*)(src + 4);
    bf16x8 o;
    o[0] = (__bf16)v0[0]; o[1] = (__bf16)v0[1]; o[2] = (__bf16)v0[2]; o[3] = (__bf16)v0[3];
    o[4] = (__bf16)v1[0]; o[5] = (__bf16)v1[1]; o[6] = (__bf16)v1[2]; o[7] = (__bf16)v1[3];
    *(bf16x8*)(xb + (idx8 << 3)) = o;
  } else if (bid < 24576) {
    size_t i8 = (size_t)(bid - 8192) * 256 + threadIdx.x;
    const float* src = w1 + (i8 << 3);
    f32x4 v0 = *(const f32x4*)src;
    f32x4 v1 = *(const f32x4*)(src + 4);
    bf16x8 o;
    o[0] = (__bf16)v0[0]; o[1] = (__bf16)v0[1]; o[2] = (__bf16)v0[2]; o[3] = (__bf16)v0[3];
    o[4] = (__bf16)v1[0]; o[5] = (__bf16)v1[1]; o[6] = (__bf16)v1[2]; o[7] = (__bf16)v1[3];
    *(bf16x8*)(w1b + (i8 << 3)) = o;
  } else {
    const int tb = bid - 24576;
    const int z = tb >> 10;
    const int rem = tb & 1023;
    const int m0 = (rem & 15) * 64;
    const int h0 = (rem >> 4) * 64;
    const int tid = threadIdx.x;
    const int cg = tid & 15, rg = tid >> 4;
#pragma unroll
    for (int p = 0; p < 4; ++p) {
      int hl = rg + p * 16;
      f32x4 v = *(const f32x4*)(w2 + (((size_t)z * Hh + h0 + hl) << 10) + m0 + (cg << 2));
#pragma unroll
      for (int i = 0; i < 4; ++i) tile[(cg << 2) + i][hl] = (__bf16)v[i];
    }
    __syncthreads();
#pragma unroll
    for (int p = 0; p < 4; ++p) {
      int ml = rg + p * 16;
      uint2 pk = *(const uint2*)(&tile[ml][cg << 2]);
      *(uint2*)(w2t + ((size_t)z * Mm + m0 + ml) * Hh + h0 + (cg << 2)) = pk;
    }
  }
}

// ---------------------------------------------------------------------------
// Standalone prepasses (fallback Paths C/D).
// ---------------------------------------------------------------------------
__global__ __launch_bounds__(256) void cvt_x_kernel(
    const float* __restrict__ x, __bf16* __restrict__ xb, int e0) {
  size_t idx8 = (size_t)blockIdx.x * 256 + threadIdx.x;
  int m8 = (int)(idx8 & 127);
  int t = (int)((idx8 >> 7) & 2047);
  int z = (int)(idx8 >> 18);
  int b = t >> 9, c = t & 511, e = e0 + z;
  const float* src = x + ((((size_t)b * Ee + e) * Cc + c) << 10) + (m8 << 3);
  f32x4 v0 = *(const f32x4*)src;
  f32x4 v1 = *(const f32x4*)(src + 4);
  bf16x8 o;
  o[0] = (__bf16)v0[0]; o[1] = (__bf16)v0[1]; o[2] = (__bf16)v0[2]; o[3] = (__bf16)v0[3];
  o[4] = (__bf16)v1[0]; o[5] = (__bf16)v1[1]; o[6] = (__bf16)v1[2]; o[7] = (__bf16)v1[3];
  *(bf16x8*)(xb + (idx8 << 3)) = o;
}

__global__ __launch_bounds__(256) void cvt_lin_kernel(
    const float* __restrict__ in, __bf16* __restrict__ outb) {
  size_t i8 = (size_t)blockIdx.x * 256 + threadIdx.x;
  const float* src = in + (i8 << 3);
  f32x4 v0 = *(const f32x4*)src;
  f32x4 v1 = *(const f32x4*)(src + 4);
  bf16x8 o;
  o[0] = (__bf16)v0[0]; o[1] = (__bf16)v0[1]; o[2] = (__bf16)v0[2]; o[3] = (__bf16)v0[3];
  o[4] = (__bf16)v1[0]; o[5] = (__bf16)v1[1]; o[6] = (__bf16)v1[2]; o[7] = (__bf16)v1[3];
  *(bf16x8*)(outb + (i8 << 3)) = o;
}

__global__ __launch_bounds__(256) void tr_w2_kernel(
    const float* __restrict__ w2, __bf16* __restrict__ w2t, int e0) {
  __shared__ __bf16 tile[64][68];
  const int z = blockIdx.z, e = e0 + z;
  const int m0 = blockIdx.x * 64, h0 = blockIdx.y * 64;
  const int tid = threadIdx.x;
  const int cg = tid & 15, rg = tid >> 4;
#pragma unroll
  for (int p = 0; p < 4; ++p) {
    int hl = rg + p * 16;
    f32x4 v = *(const f32x4*)(w2 + (((size_t)e * Hh + h0 + hl) << 10) + m0 + (cg << 2));
#pragma unroll
    for (int i = 0; i < 4; ++i) tile[(cg << 2) + i][hl] = (__bf16)v[i];
  }
  __syncthreads();
#pragma unroll
  for (int p = 0; p < 4; ++p) {
    int ml = rg + p * 16;
    uint2 pk = *(const uint2*)(&tile[ml][cg << 2]);
    *(uint2*)(w2t + ((size_t)z * Mm + m0 + ml) * Hh + h0 + (cg << 2)) = pk;
  }
}

// ---------------------------------------------------------------------------
extern "C" void kernel_launch(void* const* d_in, const int* in_sizes, int n_in,
                              void* d_out, int out_size, void* d_ws, size_t ws_size,
                              hipStream_t stream) {
  const float* x  = (const float*)d_in[0];
  const float* w1 = (const float*)d_in[1];
  const float* b1 = (const float*)d_in[2];
  const float* w2 = (const float*)d_in[3];
  const float* b2 = (const float*)d_in[4];
  float* out = (float*)d_out;

  const size_t xbS = (size_t)Tt * Mm * 2;  //  4 MiB / expert
  const size_t w1S = (size_t)Hh * Mm * 2;  //  8 MiB / expert
  const size_t w2S = (size_t)Mm * Hh * 2;  //  8 MiB / expert
  const size_t hbS = (size_t)Tt * Hh * 2;  // 16 MiB / expert
  char* ws = (char*)d_ws;

  if (ws_size >= Ee * (xbS + w1S + w2S + hbS)) {
    // Path A: everything resident. Merged prepass; persistent fc1; full fc2.
    __bf16* xb  = (__bf16*)ws;
    __bf16* w1b = (__bf16*)(ws + Ee * xbS);
    __bf16* w2t = (__bf16*)(ws + Ee * (xbS + w1S));
    __bf16* hb  = (__bf16*)(ws + Ee * (xbS + w1S + w2S));
    prep_all_kernel<<<32768, 256, 0, stream>>>(x, w1, w2, xb, w1b, w2t);
    fc1p_kernel<<<32 * Ee, 512, 0, stream>>>(xb, 0, w1b, 0, b1, hb, 0, Tt);
    fc2g_kernel<<<(Mm / 256) * (Tt / 256) * Ee, 512, 0, stream>>>(hb, Tt, w2t, 0, b2, out, 0, 0, Tt / 256);
  } else if (ws_size >= Ee * (xbS + w1S + w2S) + hbS) {
    // Path B: conversions resident; hb grouped.
    __bf16* xb  = (__bf16*)ws;
    __bf16* w1b = (__bf16*)(ws + Ee * xbS);
    __bf16* w2t = (__bf16*)(ws + Ee * (xbS + w1S));
    __bf16* hb  = (__bf16*)(ws + Ee * (xbS + w1S + w2S));
    int Gh = (int)((ws_size - Ee * (xbS + w1S + w2S)) / hbS);
    if (Gh > Ee) Gh = Ee;
    prep_all_kernel<<<32768, 256, 0, stream>>>(x, w1, w2, xb, w1b, w2t);
    for (int e0 = 0; e0 < Ee; e0 += Gh) {
      int g = (Ee - e0) < Gh ? (Ee - e0) : Gh;
      fc1p_kernel<<<32 * g, 512, 0, stream>>>(xb, e0, w1b, e0, b1, hb, e0, Tt);
      fc2g_kernel<<<(Mm / 256) * (Tt / 256) * g, 512, 0, stream>>>(hb, Tt, w2t, e0, b2, out, e0, 0, Tt / 256);
    }
  } else if (ws_size >= xbS + w1S + w2S + hbS) {
    // Path C: full pipeline grouped by G experts.
    int G = (int)(ws_size / (xbS + w1S + w2S + hbS));
    if (G > Ee) G = Ee;
    __bf16* xb  = (__bf16*)ws;
    __bf16* w1b = (__bf16*)(ws + (size_t)G * xbS);
    __bf16* w2t = (__bf16*)(ws + (size_t)G * (xbS + w1S));
    __bf16* hb  = (__bf16*)(ws + (size_t)G * (xbS + w1S + w2S));
    for (int e0 = 0; e0 < Ee; e0 += G) {
      int g = (Ee - e0) < G ? (Ee - e0) : G;
      cvt_x_kernel<<<g * 1024, 256, 0, stream>>>(x, xb, e0);
      cvt_lin_kernel<<<g * 2048, 256, 0, stream>>>(w1 + (size_t)e0 * Hh * Mm, w1b);
      tr_w2_kernel<<<dim3(Mm / 64, Hh / 64, g), 256, 0, stream>>>(w2, w2t, e0);
      fc1p_kernel<<<32 * g, 512, 0, stream>>>(xb, 0, w1b, 0, b1, hb, e0, Tt);
      fc2g_kernel<<<(Mm / 256) * (Tt / 256) * g, 512, 0, stream>>>(hb, Tt, w2t, 0, b2, out, e0, 0, Tt / 256);
    }
  } else {
    // Path D: one expert, T chunked.
    __bf16* xb  = (__bf16*)ws;
    __bf16* w1b = (__bf16*)(ws + xbS);
    __bf16* w2t = (__bf16*)(ws + xbS + w1S);
    __bf16* hb  = (__bf16*)(ws + xbS + w1S + w2S);
    size_t rem = ws_size > (xbS + w1S + w2S) ? ws_size - (xbS + w1S + w2S) : 0;
    int Tc = (int)(rem / ((size_t)Hh * 2)) & ~255;
    if (Tc > Tt) Tc = Tt;
    if (Tc < 256) Tc = 256;
    for (int e0 = 0; e0 < Ee; ++e0) {
      cvt_x_kernel<<<1024, 256, 0, stream>>>(x, xb, e0);
      cvt_lin_kernel<<<2048, 256, 0, stream>>>(w1 + (size_t)e0 * Hh * Mm, w1b);
      tr_w2_kernel<<<dim3(Mm / 64, Hh / 64, 1), 256, 0, stream>>>(w2, w2t, e0);
      for (int t0 = 0; t0 < Tt; t0 += Tc) {
        int tc = (Tt - t0) < Tc ? (Tt - t0) : Tc;
        fc1g_kernel<<<(Hh / 256) * (tc / 256), 512, 0, stream>>>(xb, 0, w1b, 0, b1, hb, e0, t0, Tc, tc / 256);
        fc2g_kernel<<<(Mm / 256) * (tc / 256), 512, 0, stream>>>(hb, Tc, w2t, 0, b2, out, e0, t0, tc / 256);
      }
    }
  }
}

// Round 15
// 455.116 us; speedup vs baseline: 1.0724x; 1.0107x over previous
//
#include <hip/hip_runtime.h>
#include <hip/hip_bf16.h>

typedef __bf16 bf16x8 __attribute__((ext_vector_type(8)));
typedef __bf16 bf16x4 __attribute__((ext_vector_type(4)));
typedef float  f32x4  __attribute__((ext_vector_type(4)));

constexpr int Ee = 8, Cc = 512, Mm = 1024, Hh = 4096, Tt = 2048;

// async global->LDS, 16B/lane. LDS dest wave-uniform base + lane*16 (m97/m104).
__device__ __forceinline__ void async16(void* lds, const void* g) {
  __builtin_amdgcn_global_load_lds(
      (const __attribute__((address_space(1))) void*)g,
      (__attribute__((address_space(3))) void*)lds, 16, 0, 0);
}

#define FENCE() asm volatile("" ::: "memory")
#define BARRIER() do { FENCE(); __builtin_amdgcn_s_barrier(); FENCE(); } while (0)

// Bijective XCD-chunked swizzle (m204).
__device__ __forceinline__ int xcd_swz(int id, int n) {
  const int q = n >> 3, r = n & 7;
  const int x = id & 7, k = id >> 3;
  return (x < r ? x * (q + 1) : r * (q + 1) + (x - r) * q) + k;
}

// ---------------------------------------------------------------------------
// 256x256 GEMM, BK=64, 8 waves (2M x 4N), 2 barriers/K-tile. [r5 CORE —
// best measured 189us/727TF fc1. Structural levers ALL measured worse:
// r7 4-phase 208, r8/r10 1-barrier-3buf 196, r11 t-fastest 255, r14
// persistence 220. This round: setprio REMOVED (T5 regime-gate: m190 shows
// setprio hurts ~1.5% on lockstep 2-barrier structures like this one).]
// Ledger (r5-verified): per tile stage B(t+1) at entry (slot fenced by the
// previous boundary barrier), read aF[0..7]+bF(ni01), BARRIER (A-slot WAR),
// stage A(t+2), 32 MFMA, read bF(ni23), 32 MFMA, vmcnt(4) [tail vmcnt(0)],
// BARRIER. Prologue: A0,B0,A1 (12 loads); vmcnt(4); BARRIER.
// LDS swizzle: phys 16B-blk = logical ^ (row&7), via pre-swizzled global
// source (rule #21 both-sides involution). 0 bank conflicts (r4-r14).
// ---------------------------------------------------------------------------
#define GEOM_LOCALS \
  const int tid = threadIdx.x; \
  const int lane = tid & 63, wid = tid >> 6; \
  const int l8 = lane >> 3; \
  const int colSwzE = (((lane & 7) ^ l8) << 3); \
  const int NT = K >> 6;

#define STAGE_IMPL \
  auto STAGE = [&](int s, int u) { \
    if (s >= NT) return; \
    const int d = s & 1; \
    if (u < 2) { \
      const __bf16* src = aT + (size_t)(u * 128 + wid * 16 + l8) * K + s * 64 + colSwzE; \
      _Pragma("unroll") \
      for (int i = 0; i < 2; ++i) \
        async16(&Ab[d][u][wid * 16 + i * 8][0], src + (size_t)(i * 8) * K); \
    } else { \
      const __bf16* src = bT + (size_t)((u - 2) * 128 + wid * 16 + l8) * K + s * 64 + colSwzE; \
      _Pragma("unroll") \
      for (int i = 0; i < 2; ++i) \
        async16(&Bb[d][u - 2][wid * 16 + i * 8][0], src + (size_t)(i * 8) * K); \
    } \
  };

__device__ __forceinline__ void gemm_pro(
    const __bf16* __restrict__ aT, const __bf16* __restrict__ bT, const int K,
    __bf16 (*Ab)[2][128][64], __bf16 (*Bb)[2][128][64]) {
  GEOM_LOCALS
  STAGE_IMPL
  STAGE(0, 0); STAGE(0, 1); STAGE(0, 2); STAGE(0, 3);
  STAGE(1, 0); STAGE(1, 1);
}

__device__ __forceinline__ void gemm_body(
    const __bf16* __restrict__ aT, const __bf16* __restrict__ bT, const int K,
    __bf16 (*Ab)[2][128][64], __bf16 (*Bb)[2][128][64],
    f32x4 (&acc)[8][4]) {
  GEOM_LOCALS
  STAGE_IMPL
  const int wr = wid >> 2, wcn = wid & 3;
  int pblk[2];
  pblk[0] = (lane >> 4) ^ (lane & 7);
  pblk[1] = (4 + (lane >> 4)) ^ (lane & 7);

  bf16x8 aF[8][2];
  bf16x8 bF[2][2];

  asm volatile("s_waitcnt vmcnt(4)" ::: "memory");
  BARRIER();

  for (int t = 0; t < NT; ++t) {
    const int d = t & 1;
    const char* pa = (const char*)&Ab[d][wr][0][0];
    const char* pb = (const char*)&Bb[d][wcn >> 1][0][0];
    const int brow = (wcn & 1) * 64;

    STAGE(t + 1, 2); STAGE(t + 1, 3);

#pragma unroll
    for (int mi = 0; mi < 8; ++mi)
#pragma unroll
      for (int kh = 0; kh < 2; ++kh)
        aF[mi][kh] = *(const bf16x8*)(pa + (mi * 16 + (lane & 15)) * 128 + pblk[kh] * 16);
#pragma unroll
    for (int ni = 0; ni < 2; ++ni)
#pragma unroll
      for (int kh = 0; kh < 2; ++kh)
        bF[ni][kh] = *(const bf16x8*)(pb + (brow + ni * 16 + (lane & 15)) * 128 + pblk[kh] * 16);

    BARRIER();  // A-slot WAR fence

    STAGE(t + 2, 0); STAGE(t + 2, 1);

#pragma unroll
    for (int mi = 0; mi < 8; ++mi)
#pragma unroll
      for (int ni = 0; ni < 2; ++ni)
#pragma unroll
        for (int kh = 0; kh < 2; ++kh)
          acc[mi][ni] = __builtin_amdgcn_mfma_f32_16x16x32_bf16(bF[ni][kh], aF[mi][kh], acc[mi][ni], 0, 0, 0);

#pragma unroll
    for (int ni = 0; ni < 2; ++ni)
#pragma unroll
      for (int kh = 0; kh < 2; ++kh)
        bF[ni][kh] = *(const bf16x8*)(pb + (brow + (2 + ni) * 16 + (lane & 15)) * 128 + pblk[kh] * 16);

#pragma unroll
    for (int mi = 0; mi < 8; ++mi)
#pragma unroll
      for (int ni = 0; ni < 2; ++ni)
#pragma unroll
        for (int kh = 0; kh < 2; ++kh)
          acc[mi][2 + ni] = __builtin_amdgcn_mfma_f32_16x16x32_bf16(bF[ni][kh], aF[mi][kh], acc[mi][2 + ni], 0, 0, 0);

    if (t < NT - 2) { asm volatile("s_waitcnt vmcnt(4)" ::: "memory"); }
    else            { asm volatile("s_waitcnt vmcnt(0)" ::: "memory"); }
    BARRIER();
  }
}

// ---------------------------------------------------------------------------
// fc1: h = relu(xb @ w1b^T + b1) -> bf16 hb.  acc is C^T: row=n, col=t.
// Full-width 1024-block dispatch (r5-proven). n-fastest decode.
// ---------------------------------------------------------------------------
__global__ __launch_bounds__(512, 2) void fc1g_kernel(
    const __bf16* __restrict__ xb, int eOffA,
    const __bf16* __restrict__ w1b, int eOffB,
    const float* __restrict__ b1, __bf16* __restrict__ hb,
    int e0, int t_base, int tcap, int nbT) {
  __shared__ __bf16 Ab[2][2][128][64];
  __shared__ __bf16 Bb[2][2][128][64];
  const int nbN = Hh / 256;
  const int id = xcd_swz(blockIdx.x, gridDim.x);
  const int z = id / (nbN * nbT);
  const int rm = id % (nbN * nbT);
  const int tblk = (rm / nbN) * 256, nblk = (rm % nbN) * 256;
  const int lane = threadIdx.x & 63, wid = threadIdx.x >> 6;
  const int wr = wid >> 2, wcn = wid & 3;

  const __bf16* aT = xb + ((size_t)(eOffA + z) * Tt + t_base + tblk) * Mm;
  const __bf16* bT = w1b + ((size_t)(eOffB + z) * Hh + nblk) * Mm;

  f32x4 acc[8][4];
#pragma unroll
  for (int i = 0; i < 8; ++i)
#pragma unroll
    for (int j = 0; j < 4; ++j) acc[i][j] = (f32x4){0.f, 0.f, 0.f, 0.f};

  gemm_pro(aT, bT, Mm, Ab, Bb);
  gemm_body(aT, bT, Mm, Ab, Bb, acc);

  const float* bias = b1 + (size_t)(e0 + z) * Hh;
#pragma unroll
  for (int ni = 0; ni < 4; ++ni) {
    const int n0 = nblk + wcn * 64 + ni * 16 + ((lane >> 4) << 2);
    const f32x4 b4 = *(const f32x4*)(bias + n0);
#pragma unroll
    for (int mi = 0; mi < 8; ++mi) {
      const int trow = tblk + wr * 128 + mi * 16 + (lane & 15);
      f32x4 v = acc[mi][ni];
      bf16x4 o;
#pragma unroll
      for (int rr = 0; rr < 4; ++rr) {
        float f = v[rr] + b4[rr];
        o[rr] = (__bf16)(f > 0.f ? f : 0.f);
      }
      *(bf16x4*)(hb + ((size_t)z * tcap + trow) * Hh + n0) = o;
    }
  }
}

// ---------------------------------------------------------------------------
// fc2: out = hb @ w2t^T + b2 -> fp32 scattered. n-fastest decode (r10).
// ---------------------------------------------------------------------------
__global__ __launch_bounds__(512, 2) void fc2g_kernel(
    const __bf16* __restrict__ hb, int tcap,
    const __bf16* __restrict__ w2t, int eOffB,
    const float* __restrict__ b2, float* __restrict__ out,
    int e0, int t_base, int nbT) {
  __shared__ __bf16 Ab[2][2][128][64];
  __shared__ __bf16 Bb[2][2][128][64];
  const int nbN = Mm / 256;
  const int id = xcd_swz(blockIdx.x, gridDim.x);
  const int z = id / (nbN * nbT);
  const int rm = id % (nbN * nbT);
  const int tblk = (rm / nbN) * 256, nblk = (rm % nbN) * 256;
  const int lane = threadIdx.x & 63, wid = threadIdx.x >> 6;
  const int wr = wid >> 2, wcn = wid & 3;
  const int e = e0 + z;

  const __bf16* aT = hb + ((size_t)z * tcap + tblk) * Hh;
  const __bf16* bT = w2t + ((size_t)(eOffB + z) * Mm + nblk) * Hh;

  f32x4 acc[8][4];
#pragma unroll
  for (int i = 0; i < 8; ++i)
#pragma unroll
    for (int j = 0; j < 4; ++j) acc[i][j] = (f32x4){0.f, 0.f, 0.f, 0.f};

  gemm_pro(aT, bT, Hh, Ab, Bb);
  gemm_body(aT, bT, Hh, Ab, Bb, acc);

  const float* bias = b2 + (size_t)e * Mm;
#pragma unroll
  for (int ni = 0; ni < 4; ++ni) {
    const int m0 = nblk + wcn * 64 + ni * 16 + ((lane >> 4) << 2);
    const f32x4 b4 = *(const f32x4*)(bias + m0);
#pragma unroll
    for (int mi = 0; mi < 8; ++mi) {
      const int t = t_base + tblk + wr * 128 + mi * 16 + (lane & 15);
      const int bb = t >> 9, cc = t & 511;
      f32x4 v = acc[mi][ni];
#pragma unroll
      for (int rr = 0; rr < 4; ++rr) v[rr] += b4[rr];
      *(f32x4*)(out + ((((size_t)bb * Ee + e) * Cc + cc) << 10) + m0) = v;
    }
  }
}

// ---------------------------------------------------------------------------
// Merged prepass (Paths A/B): one launch, all three conversions.
// ---------------------------------------------------------------------------
__global__ __launch_bounds__(256) void prep_all_kernel(
    const float* __restrict__ x, const float* __restrict__ w1,
    const float* __restrict__ w2, __bf16* __restrict__ xb,
    __bf16* __restrict__ w1b, __bf16* __restrict__ w2t) {
  __shared__ __bf16 tile[64][68];
  const int bid = blockIdx.x;
  if (bid < 8192) {
    size_t idx8 = (size_t)bid * 256 + threadIdx.x;
    int m8 = (int)(idx8 & 127);
    int t = (int)((idx8 >> 7) & 2047);
    int z = (int)(idx8 >> 18);
    int b = t >> 9, c = t & 511;
    const float* src = x + ((((size_t)b * Ee + z) * Cc + c) << 10) + (m8 << 3);
    f32x4 v0 = *(const f32x4*)src;
    f32x4 v1 = *(const f32x4*)(src + 4);
    bf16x8 o;
    o[0] = (__bf16)v0[0]; o[1] = (__bf16)v0[1]; o[2] = (__bf16)v0[2]; o[3] = (__bf16)v0[3];
    o[4] = (__bf16)v1[0]; o[5] = (__bf16)v1[1]; o[6] = (__bf16)v1[2]; o[7] = (__bf16)v1[3];
    *(bf16x8*)(xb + (idx8 << 3)) = o;
  } else if (bid < 24576) {
    size_t i8 = (size_t)(bid - 8192) * 256 + threadIdx.x;
    const float* src = w1 + (i8 << 3);
    f32x4 v0 = *(const f32x4*)src;
    f32x4 v1 = *(const f32x4*)(src + 4);
    bf16x8 o;
    o[0] = (__bf16)v0[0]; o[1] = (__bf16)v0[1]; o[2] = (__bf16)v0[2]; o[3] = (__bf16)v0[3];
    o[4] = (__bf16)v1[0]; o[5] = (__bf16)v1[1]; o[6] = (__bf16)v1[2]; o[7] = (__bf16)v1[3];
    *(bf16x8*)(w1b + (i8 << 3)) = o;
  } else {
    const int tb = bid - 24576;
    const int z = tb >> 10;
    const int rem = tb & 1023;
    const int m0 = (rem & 15) * 64;
    const int h0 = (rem >> 4) * 64;
    const int tid = threadIdx.x;
    const int cg = tid & 15, rg = tid >> 4;
#pragma unroll
    for (int p = 0; p < 4; ++p) {
      int hl = rg + p * 16;
      f32x4 v = *(const f32x4*)(w2 + (((size_t)z * Hh + h0 + hl) << 10) + m0 + (cg << 2));
#pragma unroll
      for (int i = 0; i < 4; ++i) tile[(cg << 2) + i][hl] = (__bf16)v[i];
    }
    __syncthreads();
#pragma unroll
    for (int p = 0; p < 4; ++p) {
      int ml = rg + p * 16;
      uint2 pk = *(const uint2*)(&tile[ml][cg << 2]);
      *(uint2*)(w2t + ((size_t)z * Mm + m0 + ml) * Hh + h0 + (cg << 2)) = pk;
    }
  }
}

// ---------------------------------------------------------------------------
// Standalone prepasses (fallback Paths C/D).
// ---------------------------------------------------------------------------
__global__ __launch_bounds__(256) void cvt_x_kernel(
    const float* __restrict__ x, __bf16* __restrict__ xb, int e0) {
  size_t idx8 = (size_t)blockIdx.x * 256 + threadIdx.x;
  int m8 = (int)(idx8 & 127);
  int t = (int)((idx8 >> 7) & 2047);
  int z = (int)(idx8 >> 18);
  int b = t >> 9, c = t & 511, e = e0 + z;
  const float* src = x + ((((size_t)b * Ee + e) * Cc + c) << 10) + (m8 << 3);
  f32x4 v0 = *(const f32x4*)src;
  f32x4 v1 = *(const f32x4*)(src + 4);
  bf16x8 o;
  o[0] = (__bf16)v0[0]; o[1] = (__bf16)v0[1]; o[2] = (__bf16)v0[2]; o[3] = (__bf16)v0[3];
  o[4] = (__bf16)v1[0]; o[5] = (__bf16)v1[1]; o[6] = (__bf16)v1[2]; o[7] = (__bf16)v1[3];
  *(bf16x8*)(xb + (idx8 << 3)) = o;
}

__global__ __launch_bounds__(256) void cvt_lin_kernel(
    const float* __restrict__ in, __bf16* __restrict__ outb) {
  size_t i8 = (size_t)blockIdx.x * 256 + threadIdx.x;
  const float* src = in + (i8 << 3);
  f32x4 v0 = *(const f32x4*)src;
  f32x4 v1 = *(const f32x4*)(src + 4);
  bf16x8 o;
  o[0] = (__bf16)v0[0]; o[1] = (__bf16)v0[1]; o[2] = (__bf16)v0[2]; o[3] = (__bf16)v0[3];
  o[4] = (__bf16)v1[0]; o[5] = (__bf16)v1[1]; o[6] = (__bf16)v1[2]; o[7] = (__bf16)v1[3];
  *(bf16x8*)(outb + (i8 << 3)) = o;
}

__global__ __launch_bounds__(256) void tr_w2_kernel(
    const float* __restrict__ w2, __bf16* __restrict__ w2t, int e0) {
  __shared__ __bf16 tile[64][68];
  const int z = blockIdx.z, e = e0 + z;
  const int m0 = blockIdx.x * 64, h0 = blockIdx.y * 64;
  const int tid = threadIdx.x;
  const int cg = tid & 15, rg = tid >> 4;
#pragma unroll
  for (int p = 0; p < 4; ++p) {
    int hl = rg + p * 16;
    f32x4 v = *(const f32x4*)(w2 + (((size_t)e * Hh + h0 + hl) << 10) + m0 + (cg << 2));
#pragma unroll
    for (int i = 0; i < 4; ++i) tile[(cg << 2) + i][hl] = (__bf16)v[i];
  }
  __syncthreads();
#pragma unroll
  for (int p = 0; p < 4; ++p) {
    int ml = rg + p * 16;
    uint2 pk = *(const uint2*)(&tile[ml][cg << 2]);
    *(uint2*)(w2t + ((size_t)z * Mm + m0 + ml) * Hh + h0 + (cg << 2)) = pk;
  }
}

// ---------------------------------------------------------------------------
extern "C" void kernel_launch(void* const* d_in, const int* in_sizes, int n_in,
                              void* d_out, int out_size, void* d_ws, size_t ws_size,
                              hipStream_t stream) {
  const float* x  = (const float*)d_in[0];
  const float* w1 = (const float*)d_in[1];
  const float* b1 = (const float*)d_in[2];
  const float* w2 = (const float*)d_in[3];
  const float* b2 = (const float*)d_in[4];
  float* out = (float*)d_out;

  const size_t xbS = (size_t)Tt * Mm * 2;  //  4 MiB / expert
  const size_t w1S = (size_t)Hh * Mm * 2;  //  8 MiB / expert
  const size_t w2S = (size_t)Mm * Hh * 2;  //  8 MiB / expert
  const size_t hbS = (size_t)Tt * Hh * 2;  // 16 MiB / expert
  char* ws = (char*)d_ws;

  if (ws_size >= Ee * (xbS + w1S + w2S + hbS)) {
    // Path A: everything resident. Merged prepass + full-width GEMMs
    // (r5-proven config: fc1 1024 blocks, fc2 256 blocks).
    __bf16* xb  = (__bf16*)ws;
    __bf16* w1b = (__bf16*)(ws + Ee * xbS);
    __bf16* w2t = (__bf16*)(ws + Ee * (xbS + w1S));
    __bf16* hb  = (__bf16*)(ws + Ee * (xbS + w1S + w2S));
    prep_all_kernel<<<32768, 256, 0, stream>>>(x, w1, w2, xb, w1b, w2t);
    fc1g_kernel<<<(Hh / 256) * (Tt / 256) * Ee, 512, 0, stream>>>(xb, 0, w1b, 0, b1, hb, 0, 0, Tt, Tt / 256);
    fc2g_kernel<<<(Mm / 256) * (Tt / 256) * Ee, 512, 0, stream>>>(hb, Tt, w2t, 0, b2, out, 0, 0, Tt / 256);
  } else if (ws_size >= Ee * (xbS + w1S + w2S) + hbS) {
    // Path B: conversions resident; hb grouped.
    __bf16* xb  = (__bf16*)ws;
    __bf16* w1b = (__bf16*)(ws + Ee * xbS);
    __bf16* w2t = (__bf16*)(ws + Ee * (xbS + w1S));
    __bf16* hb  = (__bf16*)(ws + Ee * (xbS + w1S + w2S));
    int Gh = (int)((ws_size - Ee * (xbS + w1S + w2S)) / hbS);
    if (Gh > Ee) Gh = Ee;
    prep_all_kernel<<<32768, 256, 0, stream>>>(x, w1, w2, xb, w1b, w2t);
    for (int e0 = 0; e0 < Ee; e0 += Gh) {
      int g = (Ee - e0) < Gh ? (Ee - e0) : Gh;
      fc1g_kernel<<<(Hh / 256) * (Tt / 256) * g, 512, 0, stream>>>(xb, e0, w1b, e0, b1, hb, e0, 0, Tt, Tt / 256);
      fc2g_kernel<<<(Mm / 256) * (Tt / 256) * g, 512, 0, stream>>>(hb, Tt, w2t, e0, b2, out, e0, 0, Tt / 256);
    }
  } else if (ws_size >= xbS + w1S + w2S + hbS) {
    // Path C: full pipeline grouped by G experts.
    int G = (int)(ws_size / (xbS + w1S + w2S + hbS));
    if (G > Ee) G = Ee;
    __bf16* xb  = (__bf16*)ws;
    __bf16* w1b = (__bf16*)(ws + (size_t)G * xbS);
    __bf16* w2t = (__bf16*)(ws + (size_t)G * (xbS + w1S));
    __bf16* hb  = (__bf16*)(ws + (size_t)G * (xbS + w1S + w2S));
    for (int e0 = 0; e0 < Ee; e0 += G) {
      int g = (Ee - e0) < G ? (Ee - e0) : G;
      cvt_x_kernel<<<g * 1024, 256, 0, stream>>>(x, xb, e0);
      cvt_lin_kernel<<<g * 2048, 256, 0, stream>>>(w1 + (size_t)e0 * Hh * Mm, w1b);
      tr_w2_kernel<<<dim3(Mm / 64, Hh / 64, g), 256, 0, stream>>>(w2, w2t, e0);
      fc1g_kernel<<<(Hh / 256) * (Tt / 256) * g, 512, 0, stream>>>(xb, 0, w1b, 0, b1, hb, e0, 0, Tt, Tt / 256);
      fc2g_kernel<<<(Mm / 256) * (Tt / 256) * g, 512, 0, stream>>>(hb, Tt, w2t, 0, b2, out, e0, 0, Tt / 256);
    }
  } else {
    // Path D: one expert, T chunked.
    __bf16* xb  = (__bf16*)ws;
    __bf16* w1b = (__bf16*)(ws + xbS);
    __bf16* w2t = (__bf16*)(ws + xbS + w1S);
    __bf16* hb  = (__bf16*)(ws + xbS + w1S + w2S);
    size_t rem = ws_size > (xbS + w1S + w2S) ? ws_size - (xbS + w1S + w2S) : 0;
    int Tc = (int)(rem / ((size_t)Hh * 2)) & ~255;
    if (Tc > Tt) Tc = Tt;
    if (Tc < 256) Tc = 256;
    for (int e0 = 0; e0 < Ee; ++e0) {
      cvt_x_kernel<<<1024, 256, 0, stream>>>(x, xb, e0);
      cvt_lin_kernel<<<2048, 256, 0, stream>>>(w1 + (size_t)e0 * Hh * Mm, w1b);
      tr_w2_kernel<<<dim3(Mm / 64, Hh / 64, 1), 256, 0, stream>>>(w2, w2t, e0);
      for (int t0 = 0; t0 < Tt; t0 += Tc) {
        int tc = (Tt - t0) < Tc ? (Tt - t0) : Tc;
        fc1g_kernel<<<(Hh / 256) * (tc / 256), 512, 0, stream>>>(xb, 0, w1b, 0, b1, hb, e0, t0, Tc, tc / 256);
        fc2g_kernel<<<(Mm / 256) * (tc / 256), 512, 0, stream>>>(hb, Tc, w2t, 0, b2, out, e0, t0, tc / 256);
      }
    }
  }
}

// Round 16
// 427.190 us; speedup vs baseline: 1.1425x; 1.0654x over previous
//
#include <hip/hip_runtime.h>
#include <hip/hip_bf16.h>

typedef __bf16 bf16x8 __attribute__((ext_vector_type(8)));
typedef __bf16 bf16x4 __attribute__((ext_vector_type(4)));
typedef float  f32x4  __attribute__((ext_vector_type(4)));

constexpr int Ee = 8, Cc = 512, Mm = 1024, Hh = 4096, Tt = 2048;

// async global->LDS, 16B/lane. LDS dest wave-uniform base + lane*16 (m97/m104).
__device__ __forceinline__ void async16(void* lds, const void* g) {
  __builtin_amdgcn_global_load_lds(
      (const __attribute__((address_space(1))) void*)g,
      (__attribute__((address_space(3))) void*)lds, 16, 0, 0);
}

#define FENCE() asm volatile("" ::: "memory")
#define BARRIER() do { FENCE(); __builtin_amdgcn_s_barrier(); FENCE(); } while (0)

// Bijective XCD-chunked swizzle (m204).
__device__ __forceinline__ int xcd_swz(int id, int n) {
  const int q = n >> 3, r = n & 7;
  const int x = id & 7, k = id >> 3;
  return (x < r ? x * (q + 1) : r * (q + 1) + (x - r) * q) + k;
}

// ---------------------------------------------------------------------------
// 256x256 GEMM, BK=64, 8 waves (2M x 4N), 2 barriers/K-tile. [EXACT r5 CORE
// incl. setprio — best measured: total 427us, fc1 189us/727TF. Config ledger
// of measured-WORSE deviations (do not retry): r7 4-phase (+19us), r8/r10
// 1-barrier-3buf (+7), r11 t-fastest decode (+66), r8/r14 grouped/persistent
// launch (+130/+31), r15 merged-prep (dirty-L2 flush lands in fc1's window,
// +17) and setprio-removal (bundled in r15 regression).]
// Ledger (r5-verified): per tile stage B(t+1) at entry (slot fenced by the
// previous boundary barrier), read aF[0..7]+bF(ni01), BARRIER (A-slot WAR),
// stage A(t+2), 32 MFMA, read bF(ni23), 32 MFMA, vmcnt(4) [tail vmcnt(0)],
// BARRIER. Prologue: A0,B0,A1 (12 loads); vmcnt(4); BARRIER.
// LDS swizzle: phys 16B-blk = logical ^ (row&7), via pre-swizzled global
// source (rule #21 both-sides involution). 0 bank conflicts (r4-r15).
// ---------------------------------------------------------------------------
#define GEOM_LOCALS \
  const int tid = threadIdx.x; \
  const int lane = tid & 63, wid = tid >> 6; \
  const int l8 = lane >> 3; \
  const int colSwzE = (((lane & 7) ^ l8) << 3); \
  const int NT = K >> 6;

#define STAGE_IMPL \
  auto STAGE = [&](int s, int u) { \
    if (s >= NT) return; \
    const int d = s & 1; \
    if (u < 2) { \
      const __bf16* src = aT + (size_t)(u * 128 + wid * 16 + l8) * K + s * 64 + colSwzE; \
      _Pragma("unroll") \
      for (int i = 0; i < 2; ++i) \
        async16(&Ab[d][u][wid * 16 + i * 8][0], src + (size_t)(i * 8) * K); \
    } else { \
      const __bf16* src = bT + (size_t)((u - 2) * 128 + wid * 16 + l8) * K + s * 64 + colSwzE; \
      _Pragma("unroll") \
      for (int i = 0; i < 2; ++i) \
        async16(&Bb[d][u - 2][wid * 16 + i * 8][0], src + (size_t)(i * 8) * K); \
    } \
  };

__device__ __forceinline__ void gemm_pro(
    const __bf16* __restrict__ aT, const __bf16* __restrict__ bT, const int K,
    __bf16 (*Ab)[2][128][64], __bf16 (*Bb)[2][128][64]) {
  GEOM_LOCALS
  STAGE_IMPL
  STAGE(0, 0); STAGE(0, 1); STAGE(0, 2); STAGE(0, 3);
  STAGE(1, 0); STAGE(1, 1);
}

__device__ __forceinline__ void gemm_body(
    const __bf16* __restrict__ aT, const __bf16* __restrict__ bT, const int K,
    __bf16 (*Ab)[2][128][64], __bf16 (*Bb)[2][128][64],
    f32x4 (&acc)[8][4]) {
  GEOM_LOCALS
  STAGE_IMPL
  const int wr = wid >> 2, wcn = wid & 3;
  int pblk[2];
  pblk[0] = (lane >> 4) ^ (lane & 7);
  pblk[1] = (4 + (lane >> 4)) ^ (lane & 7);

  bf16x8 aF[8][2];
  bf16x8 bF[2][2];

  asm volatile("s_waitcnt vmcnt(4)" ::: "memory");
  BARRIER();

  for (int t = 0; t < NT; ++t) {
    const int d = t & 1;
    const char* pa = (const char*)&Ab[d][wr][0][0];
    const char* pb = (const char*)&Bb[d][wcn >> 1][0][0];
    const int brow = (wcn & 1) * 64;

    STAGE(t + 1, 2); STAGE(t + 1, 3);

#pragma unroll
    for (int mi = 0; mi < 8; ++mi)
#pragma unroll
      for (int kh = 0; kh < 2; ++kh)
        aF[mi][kh] = *(const bf16x8*)(pa + (mi * 16 + (lane & 15)) * 128 + pblk[kh] * 16);
#pragma unroll
    for (int ni = 0; ni < 2; ++ni)
#pragma unroll
      for (int kh = 0; kh < 2; ++kh)
        bF[ni][kh] = *(const bf16x8*)(pb + (brow + ni * 16 + (lane & 15)) * 128 + pblk[kh] * 16);

    BARRIER();  // A-slot WAR fence

    STAGE(t + 2, 0); STAGE(t + 2, 1);

    __builtin_amdgcn_s_setprio(1);
#pragma unroll
    for (int mi = 0; mi < 8; ++mi)
#pragma unroll
      for (int ni = 0; ni < 2; ++ni)
#pragma unroll
        for (int kh = 0; kh < 2; ++kh)
          acc[mi][ni] = __builtin_amdgcn_mfma_f32_16x16x32_bf16(bF[ni][kh], aF[mi][kh], acc[mi][ni], 0, 0, 0);
    __builtin_amdgcn_s_setprio(0);

#pragma unroll
    for (int ni = 0; ni < 2; ++ni)
#pragma unroll
      for (int kh = 0; kh < 2; ++kh)
        bF[ni][kh] = *(const bf16x8*)(pb + (brow + (2 + ni) * 16 + (lane & 15)) * 128 + pblk[kh] * 16);

    __builtin_amdgcn_s_setprio(1);
#pragma unroll
    for (int mi = 0; mi < 8; ++mi)
#pragma unroll
      for (int ni = 0; ni < 2; ++ni)
#pragma unroll
        for (int kh = 0; kh < 2; ++kh)
          acc[mi][2 + ni] = __builtin_amdgcn_mfma_f32_16x16x32_bf16(bF[ni][kh], aF[mi][kh], acc[mi][2 + ni], 0, 0, 0);
    __builtin_amdgcn_s_setprio(0);

    if (t < NT - 2) { asm volatile("s_waitcnt vmcnt(4)" ::: "memory"); }
    else            { asm volatile("s_waitcnt vmcnt(0)" ::: "memory"); }
    BARRIER();
  }
}

// ---------------------------------------------------------------------------
// fc1: h = relu(xb @ w1b^T + b1) -> bf16 hb.  acc is C^T: row=n, col=t.
// Full-width 1024-block dispatch, n-fastest decode (r5-proven).
// ---------------------------------------------------------------------------
__global__ __launch_bounds__(512, 2) void fc1g_kernel(
    const __bf16* __restrict__ xb, int eOffA,
    const __bf16* __restrict__ w1b, int eOffB,
    const float* __restrict__ b1, __bf16* __restrict__ hb,
    int e0, int t_base, int tcap, int nbT) {
  __shared__ __bf16 Ab[2][2][128][64];
  __shared__ __bf16 Bb[2][2][128][64];
  const int nbN = Hh / 256;
  const int id = xcd_swz(blockIdx.x, gridDim.x);
  const int z = id / (nbN * nbT);
  const int rm = id % (nbN * nbT);
  const int tblk = (rm / nbN) * 256, nblk = (rm % nbN) * 256;
  const int lane = threadIdx.x & 63, wid = threadIdx.x >> 6;
  const int wr = wid >> 2, wcn = wid & 3;

  const __bf16* aT = xb + ((size_t)(eOffA + z) * Tt + t_base + tblk) * Mm;
  const __bf16* bT = w1b + ((size_t)(eOffB + z) * Hh + nblk) * Mm;

  f32x4 acc[8][4];
#pragma unroll
  for (int i = 0; i < 8; ++i)
#pragma unroll
    for (int j = 0; j < 4; ++j) acc[i][j] = (f32x4){0.f, 0.f, 0.f, 0.f};

  gemm_pro(aT, bT, Mm, Ab, Bb);
  gemm_body(aT, bT, Mm, Ab, Bb, acc);

  const float* bias = b1 + (size_t)(e0 + z) * Hh;
#pragma unroll
  for (int ni = 0; ni < 4; ++ni) {
    const int n0 = nblk + wcn * 64 + ni * 16 + ((lane >> 4) << 2);
    const f32x4 b4 = *(const f32x4*)(bias + n0);
#pragma unroll
    for (int mi = 0; mi < 8; ++mi) {
      const int trow = tblk + wr * 128 + mi * 16 + (lane & 15);
      f32x4 v = acc[mi][ni];
      bf16x4 o;
#pragma unroll
      for (int rr = 0; rr < 4; ++rr) {
        float f = v[rr] + b4[rr];
        o[rr] = (__bf16)(f > 0.f ? f : 0.f);
      }
      *(bf16x4*)(hb + ((size_t)z * tcap + trow) * Hh + n0) = o;
    }
  }
}

// ---------------------------------------------------------------------------
// fc2: out = hb @ w2t^T + b2 -> fp32 scattered. n-fastest decode.
// ---------------------------------------------------------------------------
__global__ __launch_bounds__(512, 2) void fc2g_kernel(
    const __bf16* __restrict__ hb, int tcap,
    const __bf16* __restrict__ w2t, int eOffB,
    const float* __restrict__ b2, float* __restrict__ out,
    int e0, int t_base, int nbT) {
  __shared__ __bf16 Ab[2][2][128][64];
  __shared__ __bf16 Bb[2][2][128][64];
  const int nbN = Mm / 256;
  const int id = xcd_swz(blockIdx.x, gridDim.x);
  const int z = id / (nbN * nbT);
  const int rm = id % (nbN * nbT);
  const int tblk = (rm / nbN) * 256, nblk = (rm % nbN) * 256;
  const int lane = threadIdx.x & 63, wid = threadIdx.x >> 6;
  const int wr = wid >> 2, wcn = wid & 3;
  const int e = e0 + z;

  const __bf16* aT = hb + ((size_t)z * tcap + tblk) * Hh;
  const __bf16* bT = w2t + ((size_t)(eOffB + z) * Mm + nblk) * Hh;

  f32x4 acc[8][4];
#pragma unroll
  for (int i = 0; i < 8; ++i)
#pragma unroll
    for (int j = 0; j < 4; ++j) acc[i][j] = (f32x4){0.f, 0.f, 0.f, 0.f};

  gemm_pro(aT, bT, Hh, Ab, Bb);
  gemm_body(aT, bT, Hh, Ab, Bb, acc);

  const float* bias = b2 + (size_t)e * Mm;
#pragma unroll
  for (int ni = 0; ni < 4; ++ni) {
    const int m0 = nblk + wcn * 64 + ni * 16 + ((lane >> 4) << 2);
    const f32x4 b4 = *(const f32x4*)(bias + m0);
#pragma unroll
    for (int mi = 0; mi < 8; ++mi) {
      const int t = t_base + tblk + wr * 128 + mi * 16 + (lane & 15);
      const int bb = t >> 9, cc = t & 511;
      f32x4 v = acc[mi][ni];
#pragma unroll
      for (int rr = 0; rr < 4; ++rr) v[rr] += b4[rr];
      *(f32x4*)(out + ((((size_t)bb * Ee + e) * Cc + cc) << 10) + m0) = v;
    }
  }
}

// ---------------------------------------------------------------------------
// Prepasses: SEPARATE kernels (r5-proven; merged prep_all regressed fc1 by
// shifting its 160MB dirty-L2 writeback into fc1's window, r15).
// ---------------------------------------------------------------------------
__global__ __launch_bounds__(256) void cvt_x_kernel(
    const float* __restrict__ x, __bf16* __restrict__ xb, int e0) {
  size_t idx8 = (size_t)blockIdx.x * 256 + threadIdx.x;
  int m8 = (int)(idx8 & 127);
  int t = (int)((idx8 >> 7) & 2047);
  int z = (int)(idx8 >> 18);
  int b = t >> 9, c = t & 511, e = e0 + z;
  const float* src = x + ((((size_t)b * Ee + e) * Cc + c) << 10) + (m8 << 3);
  f32x4 v0 = *(const f32x4*)src;
  f32x4 v1 = *(const f32x4*)(src + 4);
  bf16x8 o;
  o[0] = (__bf16)v0[0]; o[1] = (__bf16)v0[1]; o[2] = (__bf16)v0[2]; o[3] = (__bf16)v0[3];
  o[4] = (__bf16)v1[0]; o[5] = (__bf16)v1[1]; o[6] = (__bf16)v1[2]; o[7] = (__bf16)v1[3];
  *(bf16x8*)(xb + (idx8 << 3)) = o;
}

__global__ __launch_bounds__(256) void cvt_lin_kernel(
    const float* __restrict__ in, __bf16* __restrict__ outb) {
  size_t i8 = (size_t)blockIdx.x * 256 + threadIdx.x;
  const float* src = in + (i8 << 3);
  f32x4 v0 = *(const f32x4*)src;
  f32x4 v1 = *(const f32x4*)(src + 4);
  bf16x8 o;
  o[0] = (__bf16)v0[0]; o[1] = (__bf16)v0[1]; o[2] = (__bf16)v0[2]; o[3] = (__bf16)v0[3];
  o[4] = (__bf16)v1[0]; o[5] = (__bf16)v1[1]; o[6] = (__bf16)v1[2]; o[7] = (__bf16)v1[3];
  *(bf16x8*)(outb + (i8 << 3)) = o;
}

__global__ __launch_bounds__(256) void tr_w2_kernel(
    const float* __restrict__ w2, __bf16* __restrict__ w2t, int e0) {
  __shared__ __bf16 tile[64][68];
  const int z = blockIdx.z, e = e0 + z;
  const int m0 = blockIdx.x * 64, h0 = blockIdx.y * 64;
  const int tid = threadIdx.x;
  const int cg = tid & 15, rg = tid >> 4;
#pragma unroll
  for (int p = 0; p < 4; ++p) {
    int hl = rg + p * 16;
    f32x4 v = *(const f32x4*)(w2 + (((size_t)e * Hh + h0 + hl) << 10) + m0 + (cg << 2));
#pragma unroll
    for (int i = 0; i < 4; ++i) tile[(cg << 2) + i][hl] = (__bf16)v[i];
  }
  __syncthreads();
#pragma unroll
  for (int p = 0; p < 4; ++p) {
    int ml = rg + p * 16;
    uint2 pk = *(const uint2*)(&tile[ml][cg << 2]);
    *(uint2*)(w2t + ((size_t)z * Mm + m0 + ml) * Hh + h0 + (cg << 2)) = pk;
  }
}

// ---------------------------------------------------------------------------
extern "C" void kernel_launch(void* const* d_in, const int* in_sizes, int n_in,
                              void* d_out, int out_size, void* d_ws, size_t ws_size,
                              hipStream_t stream) {
  const float* x  = (const float*)d_in[0];
  const float* w1 = (const float*)d_in[1];
  const float* b1 = (const float*)d_in[2];
  const float* w2 = (const float*)d_in[3];
  const float* b2 = (const float*)d_in[4];
  float* out = (float*)d_out;

  const size_t xbS = (size_t)Tt * Mm * 2;  //  4 MiB / expert
  const size_t w1S = (size_t)Hh * Mm * 2;  //  8 MiB / expert
  const size_t w2S = (size_t)Mm * Hh * 2;  //  8 MiB / expert
  const size_t hbS = (size_t)Tt * Hh * 2;  // 16 MiB / expert
  char* ws = (char*)d_ws;

  if (ws_size >= Ee * (xbS + w1S + w2S + hbS)) {
    // Path A: everything resident (288 MiB). EXACT r5 config (427us best):
    // 3 separate prepasses; fc1 1024 blocks; fc2 256 blocks.
    __bf16* xb  = (__bf16*)ws;
    __bf16* w1b = (__bf16*)(ws + Ee * xbS);
    __bf16* w2t = (__bf16*)(ws + Ee * (xbS + w1S));
    __bf16* hb  = (__bf16*)(ws + Ee * (xbS + w1S + w2S));
    cvt_x_kernel<<<Ee * 1024, 256, 0, stream>>>(x, xb, 0);
    cvt_lin_kernel<<<Ee * 2048, 256, 0, stream>>>(w1, w1b);
    tr_w2_kernel<<<dim3(Mm / 64, Hh / 64, Ee), 256, 0, stream>>>(w2, w2t, 0);
    fc1g_kernel<<<(Hh / 256) * (Tt / 256) * Ee, 512, 0, stream>>>(xb, 0, w1b, 0, b1, hb, 0, 0, Tt, Tt / 256);
    fc2g_kernel<<<(Mm / 256) * (Tt / 256) * Ee, 512, 0, stream>>>(hb, Tt, w2t, 0, b2, out, 0, 0, Tt / 256);
  } else if (ws_size >= Ee * (xbS + w1S + w2S) + hbS) {
    // Path B: conversions resident; hb grouped.
    __bf16* xb  = (__bf16*)ws;
    __bf16* w1b = (__bf16*)(ws + Ee * xbS);
    __bf16* w2t = (__bf16*)(ws + Ee * (xbS + w1S));
    __bf16* hb  = (__bf16*)(ws + Ee * (xbS + w1S + w2S));
    int Gh = (int)((ws_size - Ee * (xbS + w1S + w2S)) / hbS);
    if (Gh > Ee) Gh = Ee;
    cvt_x_kernel<<<Ee * 1024, 256, 0, stream>>>(x, xb, 0);
    cvt_lin_kernel<<<Ee * 2048, 256, 0, stream>>>(w1, w1b);
    tr_w2_kernel<<<dim3(Mm / 64, Hh / 64, Ee), 256, 0, stream>>>(w2, w2t, 0);
    for (int e0 = 0; e0 < Ee; e0 += Gh) {
      int g = (Ee - e0) < Gh ? (Ee - e0) : Gh;
      fc1g_kernel<<<(Hh / 256) * (Tt / 256) * g, 512, 0, stream>>>(xb, e0, w1b, e0, b1, hb, e0, 0, Tt, Tt / 256);
      fc2g_kernel<<<(Mm / 256) * (Tt / 256) * g, 512, 0, stream>>>(hb, Tt, w2t, e0, b2, out, e0, 0, Tt / 256);
    }
  } else if (ws_size >= xbS + w1S + w2S + hbS) {
    // Path C: full pipeline grouped by G experts.
    int G = (int)(ws_size / (xbS + w1S + w2S + hbS));
    if (G > Ee) G = Ee;
    __bf16* xb  = (__bf16*)ws;
    __bf16* w1b = (__bf16*)(ws + (size_t)G * xbS);
    __bf16* w2t = (__bf16*)(ws + (size_t)G * (xbS + w1S));
    __bf16* hb  = (__bf16*)(ws + (size_t)G * (xbS + w1S + w2S));
    for (int e0 = 0; e0 < Ee; e0 += G) {
      int g = (Ee - e0) < G ? (Ee - e0) : G;
      cvt_x_kernel<<<g * 1024, 256, 0, stream>>>(x, xb, e0);
      cvt_lin_kernel<<<g * 2048, 256, 0, stream>>>(w1 + (size_t)e0 * Hh * Mm, w1b);
      tr_w2_kernel<<<dim3(Mm / 64, Hh / 64, g), 256, 0, stream>>>(w2, w2t, e0);
      fc1g_kernel<<<(Hh / 256) * (Tt / 256) * g, 512, 0, stream>>>(xb, 0, w1b, 0, b1, hb, e0, 0, Tt, Tt / 256);
      fc2g_kernel<<<(Mm / 256) * (Tt / 256) * g, 512, 0, stream>>>(hb, Tt, w2t, 0, b2, out, e0, 0, Tt / 256);
    }
  } else {
    // Path D: one expert, T chunked.
    __bf16* xb  = (__bf16*)ws;
    __bf16* w1b = (__bf16*)(ws + xbS);
    __bf16* w2t = (__bf16*)(ws + xbS + w1S);
    __bf16* hb  = (__bf16*)(ws + xbS + w1S + w2S);
    size_t rem = ws_size > (xbS + w1S + w2S) ? ws_size - (xbS + w1S + w2S) : 0;
    int Tc = (int)(rem / ((size_t)Hh * 2)) & ~255;
    if (Tc > Tt) Tc = Tt;
    if (Tc < 256) Tc = 256;
    for (int e0 = 0; e0 < Ee; ++e0) {
      cvt_x_kernel<<<1024, 256, 0, stream>>>(x, xb, e0);
      cvt_lin_kernel<<<2048, 256, 0, stream>>>(w1 + (size_t)e0 * Hh * Mm, w1b);
      tr_w2_kernel<<<dim3(Mm / 64, Hh / 64, 1), 256, 0, stream>>>(w2, w2t, e0);
      for (int t0 = 0; t0 < Tt; t0 += Tc) {
        int tc = (Tt - t0) < Tc ? (Tt - t0) : Tc;
        fc1g_kernel<<<(Hh / 256) * (tc / 256), 512, 0, stream>>>(xb, 0, w1b, 0, b1, hb, e0, t0, Tc, tc / 256);
        fc2g_kernel<<<(Mm / 256) * (tc / 256), 512, 0, stream>>>(hb, Tc, w2t, 0, b2, out, e0, t0, tc / 256);
      }
    }
  }
}